// Round 1
// baseline (1184.473 us; speedup 1.0000x reference)
//
#include <hip/hip_runtime.h>
#include <hip/hip_bf16.h>
#include <math.h>

// Problem constants (match reference)
#define NN      8192
#define FF      1433
#define HID     128
#define OUTD    64
#define NH      2
#define FH      2866   // NH*FF
#define SLOPE_A 0.2f   // attention leaky
#define SLOPE_G 0.01f  // activation leaky

// ---------------------------------------------------------------------------
// CSR build
// ---------------------------------------------------------------------------
__global__ void zero_int_kernel(int* p, int n) {
    int i = blockIdx.x * blockDim.x + threadIdx.x;
    if (i < n) p[i] = 0;
}

__global__ void count_dst_kernel(const int* __restrict__ dst, int* __restrict__ cnt, int e) {
    int i = blockIdx.x * blockDim.x + threadIdx.x;
    if (i < e) atomicAdd(&cnt[dst[i]], 1);
}

// one block, 1024 threads, n = 8192 (each thread handles 8)
__global__ void scan_offsets_kernel(const int* __restrict__ cnt, int* __restrict__ off,
                                    int* __restrict__ cur, int n) {
    __shared__ int part[1024];
    int tid = threadIdx.x;
    int base = tid * 8;
    int local[8];
    int s = 0;
    #pragma unroll
    for (int i = 0; i < 8; ++i) { local[i] = s; s += cnt[base + i]; }
    part[tid] = s;
    __syncthreads();
    for (int st = 1; st < 1024; st <<= 1) {
        int v = 0;
        if (tid >= st) v = part[tid - st];
        __syncthreads();
        if (tid >= st) part[tid] += v;
        __syncthreads();
    }
    int prev = (tid > 0) ? part[tid - 1] : 0;
    #pragma unroll
    for (int i = 0; i < 8; ++i) {
        int v = prev + local[i];
        off[base + i] = v;
        cur[base + i] = v;
    }
    if (tid == 1023) off[n] = part[1023];
}

__global__ void scatter_kernel(const int* __restrict__ src, const int* __restrict__ dst,
                               int* __restrict__ cur, int* __restrict__ csr_src, int e) {
    int i = blockIdx.x * blockDim.x + threadIdx.x;
    if (i < e) {
        int p = atomicAdd(&cur[dst[i]], 1);
        csr_src[p] = src[i];
    }
}

// ---------------------------------------------------------------------------
// fp32 GEMM: C[M,Nn] = A[M,K] @ B[K,Nn]   (M,Nn multiples of 64)
// ---------------------------------------------------------------------------
__global__ void sgemm64_kernel(const float* __restrict__ A, const float* __restrict__ B,
                               float* __restrict__ C, int M, int Nn, int K) {
    __shared__ float As[16][65];
    __shared__ float Bs[16][64];
    int bm = blockIdx.y * 64, bn = blockIdx.x * 64;
    int tid = threadIdx.x;
    int tx = tid & 15, ty = tid >> 4;
    float acc[4][4] = {};
    for (int k0 = 0; k0 < K; k0 += 16) {
        for (int i = tid; i < 64 * 16; i += 256) {
            int m = i >> 4, k = i & 15;
            As[k][m] = (k0 + k < K) ? A[(size_t)(bm + m) * K + k0 + k] : 0.f;
        }
        for (int i = tid; i < 16 * 64; i += 256) {
            int k = i >> 6, n = i & 63;
            Bs[k][n] = (k0 + k < K) ? B[(size_t)(k0 + k) * Nn + bn + n] : 0.f;
        }
        __syncthreads();
        #pragma unroll
        for (int k = 0; k < 16; ++k) {
            float a[4], b[4];
            #pragma unroll
            for (int i = 0; i < 4; ++i) a[i] = As[k][ty * 4 + i];
            #pragma unroll
            for (int j = 0; j < 4; ++j) b[j] = Bs[k][tx * 4 + j];
            #pragma unroll
            for (int i = 0; i < 4; ++i)
                #pragma unroll
                for (int j = 0; j < 4; ++j)
                    acc[i][j] = fmaf(a[i], b[j], acc[i][j]);
        }
        __syncthreads();
    }
    #pragma unroll
    for (int i = 0; i < 4; ++i)
        #pragma unroll
        for (int j = 0; j < 4; ++j)
            C[(size_t)(bm + ty * 4 + i) * Nn + bn + tx * 4 + j] = acc[i][j];
}

// ---------------------------------------------------------------------------
// attention scores: el[n,h] = sum_d h[n,h,d]*al[h,d] ; er likewise
// layout hf: [N, NH*D]; one wave per (n,h); rows = N*NH
// ---------------------------------------------------------------------------
template<int D>
__global__ void attn_scores_kernel(const float* __restrict__ hf, const float* __restrict__ al,
                                   const float* __restrict__ ar, float* __restrict__ el,
                                   float* __restrict__ er, int rows) {
    int wid = (blockIdx.x * blockDim.x + threadIdx.x) >> 6;
    int lane = threadIdx.x & 63;
    if (wid >= rows) return;
    int n = wid >> 1, h = wid & 1;
    const float* row = hf + (size_t)n * (NH * D) + h * D;
    float sl = 0.f, sr = 0.f;
    #pragma unroll
    for (int d = lane; d < D; d += 64) {
        float v = row[d];
        sl = fmaf(v, al[h * D + d], sl);
        sr = fmaf(v, ar[h * D + d], sr);
    }
    #pragma unroll
    for (int o = 32; o > 0; o >>= 1) { sl += __shfl_xor(sl, o); sr += __shfl_xor(sr, o); }
    if (lane == 0) { el[wid] = sl; er[wid] = sr; }
}

// el3[n,h] = sum_k z[n,k]*wl[h,k]  (z shared across heads, D=64)
__global__ void attn_scores_shared_kernel(const float* __restrict__ z, const float* __restrict__ wl,
                                          const float* __restrict__ wr, float* __restrict__ el,
                                          float* __restrict__ er, int rows) {
    int wid = (blockIdx.x * blockDim.x + threadIdx.x) >> 6;
    int lane = threadIdx.x & 63;
    if (wid >= rows) return;
    int n = wid >> 1, h = wid & 1;
    float v = z[(size_t)n * 64 + lane];
    float sl = v * wl[h * 64 + lane];
    float sr = v * wr[h * 64 + lane];
    #pragma unroll
    for (int o = 32; o > 0; o >>= 1) { sl += __shfl_xor(sl, o); sr += __shfl_xor(sr, o); }
    if (lane == 0) { el[wid] = sl; er[wid] = sr; }
}

// wl[h,k] = sum_f W3[k, h*FF+f]*al3[h,f]  -- 128 waves
__global__ void w3_vec_kernel(const float* __restrict__ W3, const float* __restrict__ al3,
                              const float* __restrict__ ar3, float* __restrict__ wl,
                              float* __restrict__ wr) {
    int wid = (blockIdx.x * blockDim.x + threadIdx.x) >> 6;
    int lane = threadIdx.x & 63;
    if (wid >= 128) return;
    int h = wid >> 6, k = wid & 63;
    const float* row = W3 + (size_t)k * FH + h * FF;
    const float* a = al3 + h * FF;
    const float* b = ar3 + h * FF;
    float sl = 0.f, sr = 0.f;
    for (int f = lane; f < FF; f += 64) {
        float w = row[f];
        sl = fmaf(w, a[f], sl);
        sr = fmaf(w, b[f], sr);
    }
    #pragma unroll
    for (int o = 32; o > 0; o >>= 1) { sl += __shfl_xor(sl, o); sr += __shfl_xor(sr, o); }
    if (lane == 0) { wl[wid] = sl; wr[wid] = sr; }
}

// ---------------------------------------------------------------------------
// GAT aggregation: one wave per (dst-node, head).
// Pass 1: online softmax (m, s) over incoming edges.
// Pass 2: acc[d] = sum_e alpha_e * feat[src_e, (h), d]; out[n, h*D+d] = acc.
// SHARED_FEAT: feat row is n*D (layer 3, z); else n*(NH*D)+h*D.
// ---------------------------------------------------------------------------
template<int D, bool SHARED_FEAT>
__global__ void gat_aggregate_kernel(const int* __restrict__ off, const int* __restrict__ csr_src,
                                     const float* __restrict__ el, const float* __restrict__ er,
                                     const float* __restrict__ feat, float* __restrict__ out,
                                     int rows) {
    int wid = (blockIdx.x * blockDim.x + threadIdx.x) >> 6;
    int lane = threadIdx.x & 63;
    if (wid >= rows) return;
    int n = wid >> 1, h = wid & 1;
    int start = off[n], end = off[n + 1];
    float ern = er[wid];

    // pass 1: online max / sum of exp
    float m = -1e30f, s = 0.f;
    for (int base = start; base < end; base += 64) {
        int j = base + lane;
        float e = -1e30f;
        if (j < end) {
            int sN = csr_src[j];
            float x = el[sN * 2 + h] + ern;
            e = x > 0.f ? x : SLOPE_A * x;
        }
        float cm = e;
        #pragma unroll
        for (int o = 32; o > 0; o >>= 1) cm = fmaxf(cm, __shfl_xor(cm, o));
        float nm = fmaxf(m, cm);
        float add = (j < end) ? expf(e - nm) : 0.f;
        #pragma unroll
        for (int o = 32; o > 0; o >>= 1) add += __shfl_xor(add, o);
        s = s * expf(m - nm) + add;
        m = nm;
    }
    float inv_s = 1.f / s;

    // pass 2: aggregate
    constexpr int PER = (D + 63) / 64;
    float acc[PER];
    #pragma unroll
    for (int i = 0; i < PER; ++i) acc[i] = 0.f;
    for (int j = start; j < end; ++j) {
        int sN = csr_src[j];
        float x = el[sN * 2 + h] + ern;
        float e = x > 0.f ? x : SLOPE_A * x;
        float a = expf(e - m) * inv_s;
        const float* row = SHARED_FEAT ? (feat + (size_t)sN * D)
                                       : (feat + (size_t)sN * (NH * D) + h * D);
        #pragma unroll
        for (int i = 0; i < PER; ++i) acc[i] = fmaf(a, row[lane + 64 * i], acc[i]);
    }
    float* orow = out + (size_t)n * (NH * D) + h * D;
    #pragma unroll
    for (int i = 0; i < PER; ++i) orow[lane + 64 * i] = acc[i];
}

// ---------------------------------------------------------------------------
// epilogues
// ---------------------------------------------------------------------------
__global__ void ep1_kernel(const float* __restrict__ agg, const float* __restrict__ b,
                           float* __restrict__ out, int total) {   // total = N*256
    int i = blockIdx.x * blockDim.x + threadIdx.x;
    if (i >= total) return;
    int c = i & 255;
    float v = agg[i] + b[c];
    out[i] = v > 0.f ? v : SLOPE_G * v;
}

__global__ void ep2_kernel(const float* __restrict__ agg, const float* __restrict__ b,
                           float* __restrict__ z, int total) {     // total = N*64
    int i = blockIdx.x * blockDim.x + threadIdx.x;
    if (i >= total) return;
    int n = i >> 6, d = i & 63;
    float v0 = agg[(size_t)n * 128 + d] + b[d];
    v0 = v0 > 0.f ? v0 : SLOPE_G * v0;
    float v1 = agg[(size_t)n * 128 + 64 + d] + b[64 + d];
    v1 = v1 > 0.f ? v1 : SLOPE_G * v1;
    z[i] = 0.5f * (v0 + v1);
}

// ---------------------------------------------------------------------------
// x_hat[n,f] = 0.5 * sum_h lrelu( zagg[n,h,:]@W3[:,h*FF+f] + b3[h*FF+f] )
// 8 nodes per block, 256 threads over f
// ---------------------------------------------------------------------------
__global__ void xhat_kernel(const float* __restrict__ zagg, const float* __restrict__ W3,
                            const float* __restrict__ b3, float* __restrict__ xhat) {
    __shared__ float zs[8][128];
    int n0 = blockIdx.x * 8;
    int tid = threadIdx.x;
    for (int i = tid; i < 8 * 128; i += 256) zs[i >> 7][i & 127] = zagg[(size_t)n0 * 128 + i];
    __syncthreads();
    for (int f = tid; f < FF; f += 256) {
        float acc0[8] = {}, acc1[8] = {};
        const float* w0 = W3 + f;
        const float* w1 = W3 + FF + f;
        for (int k = 0; k < 64; ++k) {
            float wv0 = w0[(size_t)k * FH];
            float wv1 = w1[(size_t)k * FH];
            #pragma unroll
            for (int i = 0; i < 8; ++i) {
                acc0[i] = fmaf(zs[i][k], wv0, acc0[i]);
                acc1[i] = fmaf(zs[i][64 + k], wv1, acc1[i]);
            }
        }
        float b0 = b3[f], b1 = b3[FF + f];
        #pragma unroll
        for (int i = 0; i < 8; ++i) {
            float v0 = acc0[i] + b0; v0 = v0 > 0.f ? v0 : SLOPE_G * v0;
            float v1 = acc1[i] + b1; v1 = v1 > 0.f ? v1 : SLOPE_G * v1;
            xhat[(size_t)(n0 + i) * FF + f] = 0.5f * (v0 + v1);
        }
    }
}

// ---------------------------------------------------------------------------
// a_hat = z @ z^T  (K = 64), 64x64 tile per block
// ---------------------------------------------------------------------------
__global__ void ahat_kernel(const float* __restrict__ z, float* __restrict__ out) {
    __shared__ float Zr[64][65];
    __shared__ float Zc[64][65];
    int bx = blockIdx.x, by = blockIdx.y;
    int tid = threadIdx.x;
    for (int i = tid; i < 64 * 64; i += 256) {
        int r = i >> 6, k = i & 63;
        Zr[r][k] = z[(size_t)(by * 64 + r) * 64 + k];
        Zc[r][k] = z[(size_t)(bx * 64 + r) * 64 + k];
    }
    __syncthreads();
    int tx = tid & 15, ty = tid >> 4;
    float acc[4][4] = {};
    #pragma unroll
    for (int k = 0; k < 64; ++k) {
        float a[4], b[4];
        #pragma unroll
        for (int i = 0; i < 4; ++i) { a[i] = Zr[ty * 4 + i][k]; b[i] = Zc[tx * 4 + i][k]; }
        #pragma unroll
        for (int i = 0; i < 4; ++i)
            #pragma unroll
            for (int j = 0; j < 4; ++j)
                acc[i][j] = fmaf(a[i], b[j], acc[i][j]);
    }
    #pragma unroll
    for (int i = 0; i < 4; ++i)
        #pragma unroll
        for (int j = 0; j < 4; ++j)
            out[(size_t)(by * 64 + ty * 4 + i) * NN + bx * 64 + tx * 4 + j] = acc[i][j];
}

// ---------------------------------------------------------------------------
extern "C" void kernel_launch(void* const* d_in, const int* in_sizes, int n_in,
                              void* d_out, int out_size, void* d_ws, size_t ws_size,
                              hipStream_t stream) {
    const float* feat = (const float*)d_in[0];
    const int*   src  = (const int*)d_in[1];
    const int*   dst  = (const int*)d_in[2];
    const float* W1   = (const float*)d_in[3];
    const float* al1  = (const float*)d_in[4];
    const float* ar1  = (const float*)d_in[5];
    const float* b1   = (const float*)d_in[6];
    const float* W2   = (const float*)d_in[7];
    const float* al2  = (const float*)d_in[8];
    const float* ar2  = (const float*)d_in[9];
    const float* b2   = (const float*)d_in[10];
    const float* W3   = (const float*)d_in[11];
    const float* al3  = (const float*)d_in[12];
    const float* ar3  = (const float*)d_in[13];
    const float* b3   = (const float*)d_in[14];

    const int E = in_sizes[1];
    const int rows = NN * NH;

    // ---- workspace bump allocator (256B aligned) ----
    char* ws = (char*)d_ws;
    size_t o = 0;
    auto alloc = [&](size_t bytes) -> char* {
        o = (o + 255) & ~(size_t)255;
        char* p = ws + o;
        o += bytes;
        return p;
    };
    int*   cnt     = (int*)alloc((size_t)NN * 4);
    int*   off     = (int*)alloc((size_t)(NN + 1) * 4);
    int*   cur     = (int*)alloc((size_t)NN * 4);
    int*   csr_src = (int*)alloc((size_t)E * 4);
    float* h1      = (float*)alloc((size_t)NN * 256 * 4);
    float* el1     = (float*)alloc((size_t)rows * 4);
    float* er1     = (float*)alloc((size_t)rows * 4);
    float* agg1    = (float*)alloc((size_t)NN * 256 * 4);
    float* out1    = (float*)alloc((size_t)NN * 256 * 4);
    float* h2      = (float*)alloc((size_t)NN * 128 * 4);
    float* el2     = (float*)alloc((size_t)rows * 4);
    float* er2     = (float*)alloc((size_t)rows * 4);
    float* agg2    = (float*)alloc((size_t)NN * 128 * 4);
    float* z       = (float*)alloc((size_t)NN * 64 * 4);
    float* wl3     = (float*)alloc(128 * 4);
    float* wr3     = (float*)alloc(128 * 4);
    float* el3     = (float*)alloc((size_t)rows * 4);
    float* er3     = (float*)alloc((size_t)rows * 4);
    float* zagg    = (float*)alloc((size_t)NN * 128 * 4);

    float* a_hat = (float*)d_out;
    float* x_hat = (float*)d_out + (size_t)NN * NN;

    // ---- CSR build ----
    zero_int_kernel<<<(NN + 255) / 256, 256, 0, stream>>>(cnt, NN);
    count_dst_kernel<<<(E + 255) / 256, 256, 0, stream>>>(dst, cnt, E);
    scan_offsets_kernel<<<1, 1024, 0, stream>>>(cnt, off, cur, NN);
    scatter_kernel<<<(E + 255) / 256, 256, 0, stream>>>(src, dst, cur, csr_src, E);

    // ---- layer 1 ----
    {
        dim3 g(256 / 64, NN / 64);
        sgemm64_kernel<<<g, 256, 0, stream>>>(feat, W1, h1, NN, 256, FF);
    }
    attn_scores_kernel<128><<<rows / 4, 256, 0, stream>>>(h1, al1, ar1, el1, er1, rows);
    gat_aggregate_kernel<128, false><<<rows / 4, 256, 0, stream>>>(off, csr_src, el1, er1, h1, agg1, rows);
    ep1_kernel<<<(NN * 256 + 255) / 256, 256, 0, stream>>>(agg1, b1, out1, NN * 256);

    // ---- layer 2 ----
    {
        dim3 g(128 / 64, NN / 64);
        sgemm64_kernel<<<g, 256, 0, stream>>>(out1, W2, h2, NN, 128, 256);
    }
    attn_scores_kernel<64><<<rows / 4, 256, 0, stream>>>(h2, al2, ar2, el2, er2, rows);
    gat_aggregate_kernel<64, false><<<rows / 4, 256, 0, stream>>>(off, csr_src, el2, er2, h2, agg2, rows);
    ep2_kernel<<<(NN * 64 + 255) / 256, 256, 0, stream>>>(agg2, b2, z, NN * 64);

    // ---- layer 3 (attr decoder), aggregation pushed before GEMM ----
    w3_vec_kernel<<<32, 256, 0, stream>>>(W3, al3, ar3, wl3, wr3);
    attn_scores_shared_kernel<<<rows / 4, 256, 0, stream>>>(z, wl3, wr3, el3, er3, rows);
    gat_aggregate_kernel<64, true><<<rows / 4, 256, 0, stream>>>(off, csr_src, el3, er3, z, zagg, rows);
    xhat_kernel<<<NN / 8, 256, 0, stream>>>(zagg, W3, b3, x_hat);

    // ---- structure decoder ----
    {
        dim3 g(NN / 64, NN / 64);
        ahat_kernel<<<g, 256, 0, stream>>>(z, a_hat);
    }
}

// Round 2
// 746.398 us; speedup vs baseline: 1.5869x; 1.5869x over previous
//
#include <hip/hip_runtime.h>
#include <hip/hip_bf16.h>
#include <math.h>

// Problem constants (match reference)
#define NN      8192
#define FF      1433
#define FFP     1440   // FF padded to multiple of 32
#define HID     128
#define OUTD    64
#define NH      2
#define FH      2866   // NH*FF
#define SLOPE_A 0.2f   // attention leaky
#define SLOPE_G 0.01f  // activation leaky

typedef unsigned short ushortT;
typedef __attribute__((ext_vector_type(8))) short bf16x8;
typedef __attribute__((ext_vector_type(4))) float f32x4;

__device__ inline ushortT f2bf(float x) {
    unsigned u = __float_as_uint(x);
    unsigned r = (u + 0x7FFFu + ((u >> 16) & 1u)) >> 16;
    return (ushortT)r;
}

// ---------------------------------------------------------------------------
// CSR build
// ---------------------------------------------------------------------------
__global__ void zero_int_kernel(int* p, int n) {
    int i = blockIdx.x * blockDim.x + threadIdx.x;
    if (i < n) p[i] = 0;
}

__global__ void count_dst_kernel(const int* __restrict__ dst, int* __restrict__ cnt, int e) {
    int i = blockIdx.x * blockDim.x + threadIdx.x;
    if (i < e) atomicAdd(&cnt[dst[i]], 1);
}

// one block, 1024 threads, n = 8192 (each thread handles 8)
__global__ void scan_offsets_kernel(const int* __restrict__ cnt, int* __restrict__ off,
                                    int* __restrict__ cur, int n) {
    __shared__ int part[1024];
    int tid = threadIdx.x;
    int base = tid * 8;
    int local[8];
    int s = 0;
    #pragma unroll
    for (int i = 0; i < 8; ++i) { local[i] = s; s += cnt[base + i]; }
    part[tid] = s;
    __syncthreads();
    for (int st = 1; st < 1024; st <<= 1) {
        int v = 0;
        if (tid >= st) v = part[tid - st];
        __syncthreads();
        if (tid >= st) part[tid] += v;
        __syncthreads();
    }
    int prev = (tid > 0) ? part[tid - 1] : 0;
    #pragma unroll
    for (int i = 0; i < 8; ++i) {
        int v = prev + local[i];
        off[base + i] = v;
        cur[base + i] = v;
    }
    if (tid == 1023) off[n] = part[1023];
}

__global__ void scatter_kernel(const int* __restrict__ src, const int* __restrict__ dst,
                               int* __restrict__ cur, int* __restrict__ csr_src, int e) {
    int i = blockIdx.x * blockDim.x + threadIdx.x;
    if (i < e) {
        int p = atomicAdd(&cur[dst[i]], 1);
        csr_src[p] = src[i];
    }
}

// ---------------------------------------------------------------------------
// casts
// ---------------------------------------------------------------------------
// feat [rows][cin] fp32 -> [rows][cout] bf16 zero-padded; one block per row
__global__ void cast_pad_kernel(const float* __restrict__ in, ushortT* __restrict__ out,
                                int cin, int cout) {
    int r = blockIdx.x;
    const float* irow = in + (size_t)r * cin;
    ushortT* orow = out + (size_t)r * cout;
    for (int c = threadIdx.x; c < cout; c += blockDim.x)
        orow[c] = (c < cin) ? f2bf(irow[c]) : (ushortT)0;
}

// W [K][Nn] fp32 -> WT [Nn][Kpad] bf16 zero-padded; one block per output row n
__global__ void transpose_cast_kernel(const float* __restrict__ in, ushortT* __restrict__ out,
                                      int K, int Nn, int Kpad) {
    int n = blockIdx.x;
    ushortT* orow = out + (size_t)n * Kpad;
    for (int k = threadIdx.x; k < Kpad; k += blockDim.x)
        orow[k] = (k < K) ? f2bf(in[(size_t)k * Nn + n]) : (ushortT)0;
}

// ---------------------------------------------------------------------------
// bf16 MFMA GEMM (B^T input): C[M,N] = A[M,K] @ B^T[N,K]^T, K % 32 == 0
// 128x128 tile per block, 256 threads = 4 waves (2x2), 4x4 16x16x32 frags/wave
// ---------------------------------------------------------------------------
__device__ inline void gload16(const ushortT* g, ushortT* ldsbase) {
    __builtin_amdgcn_global_load_lds(
        (const __attribute__((address_space(1))) unsigned int*)g,
        (__attribute__((address_space(3))) unsigned int*)ldsbase, 16, 0, 0);
}

__global__ __launch_bounds__(256)
void bt_mfma_kernel(const ushortT* __restrict__ A, const ushortT* __restrict__ B,
                    float* __restrict__ C, int K, int ldc) {
    __shared__ ushortT As[128 * 32];
    __shared__ ushortT Bs[128 * 32];
    const int tid = threadIdx.x;
    const int w = tid >> 6, lane = tid & 63;
    const int wr = w >> 1, wc = w & 1;
    const int brow = blockIdx.y * 128, bcol = blockIdx.x * 128;
    const int sr = lane >> 2, sk = (lane & 3) * 8;   // staging row / k within chunk

    f32x4 acc[4][4];
    #pragma unroll
    for (int i = 0; i < 4; ++i)
        #pragma unroll
        for (int j = 0; j < 4; ++j)
            acc[i][j] = (f32x4){0.f, 0.f, 0.f, 0.f};

    const ushortT* Ab = A + (size_t)brow * K;
    const ushortT* Bb = B + (size_t)bcol * K;
    const int frow = lane & 15;
    const int fk = (lane >> 4) * 8;

    for (int k0 = 0; k0 < K; k0 += 32) {
        #pragma unroll
        for (int t = 0; t < 2; ++t) {
            int c = w * 2 + t;                       // chunk 0..7, 16 rows each
            gload16(Ab + (size_t)(c * 16 + sr) * K + k0 + sk, &As[c * 512]);
            gload16(Bb + (size_t)(c * 16 + sr) * K + k0 + sk, &Bs[c * 512]);
        }
        __syncthreads();
        bf16x8 af[4], bfr[4];
        #pragma unroll
        for (int i = 0; i < 4; ++i)
            af[i] = *(const bf16x8*)&As[(wr * 64 + i * 16 + frow) * 32 + fk];
        #pragma unroll
        for (int j = 0; j < 4; ++j)
            bfr[j] = *(const bf16x8*)&Bs[(wc * 64 + j * 16 + frow) * 32 + fk];
        #pragma unroll
        for (int i = 0; i < 4; ++i)
            #pragma unroll
            for (int j = 0; j < 4; ++j)
                acc[i][j] = __builtin_amdgcn_mfma_f32_16x16x32_bf16(af[i], bfr[j], acc[i][j], 0, 0, 0);
        __syncthreads();
    }
    const int crow0 = brow + wr * 64 + (lane >> 4) * 4;
    const int ccol0 = bcol + wc * 64 + (lane & 15);
    #pragma unroll
    for (int i = 0; i < 4; ++i)
        #pragma unroll
        for (int j = 0; j < 4; ++j) {
            #pragma unroll
            for (int r = 0; r < 4; ++r)
                C[(size_t)(crow0 + i * 16 + r) * ldc + ccol0 + j * 16] = acc[i][j][r];
        }
}

// ---------------------------------------------------------------------------
// attention scores: el[n,h] = sum_d h[n,h,d]*al[h,d] ; er likewise
// ---------------------------------------------------------------------------
template<int D>
__global__ void attn_scores_kernel(const float* __restrict__ hf, const float* __restrict__ al,
                                   const float* __restrict__ ar, float* __restrict__ el,
                                   float* __restrict__ er, int rows) {
    int wid = (blockIdx.x * blockDim.x + threadIdx.x) >> 6;
    int lane = threadIdx.x & 63;
    if (wid >= rows) return;
    int n = wid >> 1, h = wid & 1;
    const float* row = hf + (size_t)n * (NH * D) + h * D;
    float sl = 0.f, sr = 0.f;
    #pragma unroll
    for (int d = lane; d < D; d += 64) {
        float v = row[d];
        sl = fmaf(v, al[h * D + d], sl);
        sr = fmaf(v, ar[h * D + d], sr);
    }
    #pragma unroll
    for (int o = 32; o > 0; o >>= 1) { sl += __shfl_xor(sl, o); sr += __shfl_xor(sr, o); }
    if (lane == 0) { el[wid] = sl; er[wid] = sr; }
}

// el3[n,h] = sum_k z[n,k]*wl[h,k]  (z shared across heads, D=64)
__global__ void attn_scores_shared_kernel(const float* __restrict__ z, const float* __restrict__ wl,
                                          const float* __restrict__ wr, float* __restrict__ el,
                                          float* __restrict__ er, int rows) {
    int wid = (blockIdx.x * blockDim.x + threadIdx.x) >> 6;
    int lane = threadIdx.x & 63;
    if (wid >= rows) return;
    int n = wid >> 1, h = wid & 1;
    float v = z[(size_t)n * 64 + lane];
    float sl = v * wl[h * 64 + lane];
    float sr = v * wr[h * 64 + lane];
    #pragma unroll
    for (int o = 32; o > 0; o >>= 1) { sl += __shfl_xor(sl, o); sr += __shfl_xor(sr, o); }
    if (lane == 0) { el[wid] = sl; er[wid] = sr; }
}

// wl[h,k] = sum_f W3[k, h*FF+f]*al3[h,f]  -- 128 waves
__global__ void w3_vec_kernel(const float* __restrict__ W3, const float* __restrict__ al3,
                              const float* __restrict__ ar3, float* __restrict__ wl,
                              float* __restrict__ wr) {
    int wid = (blockIdx.x * blockDim.x + threadIdx.x) >> 6;
    int lane = threadIdx.x & 63;
    if (wid >= 128) return;
    int h = wid >> 6, k = wid & 63;
    const float* row = W3 + (size_t)k * FH + h * FF;
    const float* a = al3 + h * FF;
    const float* b = ar3 + h * FF;
    float sl = 0.f, sr = 0.f;
    for (int f = lane; f < FF; f += 64) {
        float w = row[f];
        sl = fmaf(w, a[f], sl);
        sr = fmaf(w, b[f], sr);
    }
    #pragma unroll
    for (int o = 32; o > 0; o >>= 1) { sl += __shfl_xor(sl, o); sr += __shfl_xor(sr, o); }
    if (lane == 0) { wl[wid] = sl; wr[wid] = sr; }
}

// ---------------------------------------------------------------------------
// GAT aggregation: one wave per (dst-node, head), online softmax + gather
// ---------------------------------------------------------------------------
template<int D, bool SHARED_FEAT>
__global__ void gat_aggregate_kernel(const int* __restrict__ off, const int* __restrict__ csr_src,
                                     const float* __restrict__ el, const float* __restrict__ er,
                                     const float* __restrict__ feat, float* __restrict__ out,
                                     int rows) {
    int wid = (blockIdx.x * blockDim.x + threadIdx.x) >> 6;
    int lane = threadIdx.x & 63;
    if (wid >= rows) return;
    int n = wid >> 1, h = wid & 1;
    int start = off[n], end = off[n + 1];
    float ern = er[wid];

    // pass 1: online max / sum of exp
    float m = -1e30f, s = 0.f;
    for (int base = start; base < end; base += 64) {
        int j = base + lane;
        float e = -1e30f;
        if (j < end) {
            int sN = csr_src[j];
            float x = el[sN * 2 + h] + ern;
            e = x > 0.f ? x : SLOPE_A * x;
        }
        float cm = e;
        #pragma unroll
        for (int o = 32; o > 0; o >>= 1) cm = fmaxf(cm, __shfl_xor(cm, o));
        float nm = fmaxf(m, cm);
        float add = (j < end) ? expf(e - nm) : 0.f;
        #pragma unroll
        for (int o = 32; o > 0; o >>= 1) add += __shfl_xor(add, o);
        s = s * expf(m - nm) + add;
        m = nm;
    }
    float inv_s = 1.f / s;

    // pass 2: aggregate
    constexpr int PER = (D + 63) / 64;
    float acc[PER];
    #pragma unroll
    for (int i = 0; i < PER; ++i) acc[i] = 0.f;
    for (int j = start; j < end; ++j) {
        int sN = csr_src[j];
        float x = el[sN * 2 + h] + ern;
        float e = x > 0.f ? x : SLOPE_A * x;
        float a = expf(e - m) * inv_s;
        const float* row = SHARED_FEAT ? (feat + (size_t)sN * D)
                                       : (feat + (size_t)sN * (NH * D) + h * D);
        #pragma unroll
        for (int i = 0; i < PER; ++i) acc[i] = fmaf(a, row[lane + 64 * i], acc[i]);
    }
    float* orow = out + (size_t)n * (NH * D) + h * D;
    #pragma unroll
    for (int i = 0; i < PER; ++i) orow[lane + 64 * i] = acc[i];
}

// ---------------------------------------------------------------------------
// epilogues
// ---------------------------------------------------------------------------
__global__ void ep1_kernel(const float* __restrict__ agg, const float* __restrict__ b,
                           ushortT* __restrict__ out1b, int total) {   // total = N*256
    int i = blockIdx.x * blockDim.x + threadIdx.x;
    if (i >= total) return;
    int c = i & 255;
    float v = agg[i] + b[c];
    v = v > 0.f ? v : SLOPE_G * v;
    out1b[i] = f2bf(v);
}

__global__ void ep2_kernel(const float* __restrict__ agg, const float* __restrict__ b,
                           float* __restrict__ z, ushortT* __restrict__ zb, int total) { // N*64
    int i = blockIdx.x * blockDim.x + threadIdx.x;
    if (i >= total) return;
    int n = i >> 6, d = i & 63;
    float v0 = agg[(size_t)n * 128 + d] + b[d];
    v0 = v0 > 0.f ? v0 : SLOPE_G * v0;
    float v1 = agg[(size_t)n * 128 + 64 + d] + b[64 + d];
    v1 = v1 > 0.f ? v1 : SLOPE_G * v1;
    float zv = 0.5f * (v0 + v1);
    z[i] = zv;
    zb[i] = f2bf(zv);
}

// ---------------------------------------------------------------------------
// x_hat[n,f] = 0.5 * sum_h lrelu( zagg[n,h,:]@W3[:,h*FF+f] + b3[h*FF+f] )
// ---------------------------------------------------------------------------
__global__ void xhat_kernel(const float* __restrict__ zagg, const float* __restrict__ W3,
                            const float* __restrict__ b3, float* __restrict__ xhat) {
    __shared__ float zs[8][128];
    int n0 = blockIdx.x * 8;
    int tid = threadIdx.x;
    for (int i = tid; i < 8 * 128; i += 256) zs[i >> 7][i & 127] = zagg[(size_t)n0 * 128 + i];
    __syncthreads();
    for (int f = tid; f < FF; f += 256) {
        float acc0[8] = {}, acc1[8] = {};
        const float* w0 = W3 + f;
        const float* w1 = W3 + FF + f;
        for (int k = 0; k < 64; ++k) {
            float wv0 = w0[(size_t)k * FH];
            float wv1 = w1[(size_t)k * FH];
            #pragma unroll
            for (int i = 0; i < 8; ++i) {
                acc0[i] = fmaf(zs[i][k], wv0, acc0[i]);
                acc1[i] = fmaf(zs[i][64 + k], wv1, acc1[i]);
            }
        }
        float b0 = b3[f], b1 = b3[FF + f];
        #pragma unroll
        for (int i = 0; i < 8; ++i) {
            float v0 = acc0[i] + b0; v0 = v0 > 0.f ? v0 : SLOPE_G * v0;
            float v1 = acc1[i] + b1; v1 = v1 > 0.f ? v1 : SLOPE_G * v1;
            xhat[(size_t)(n0 + i) * FF + f] = 0.5f * (v0 + v1);
        }
    }
}

// ---------------------------------------------------------------------------
extern "C" void kernel_launch(void* const* d_in, const int* in_sizes, int n_in,
                              void* d_out, int out_size, void* d_ws, size_t ws_size,
                              hipStream_t stream) {
    const float* feat = (const float*)d_in[0];
    const int*   src  = (const int*)d_in[1];
    const int*   dst  = (const int*)d_in[2];
    const float* W1   = (const float*)d_in[3];
    const float* al1  = (const float*)d_in[4];
    const float* ar1  = (const float*)d_in[5];
    const float* b1   = (const float*)d_in[6];
    const float* W2   = (const float*)d_in[7];
    const float* al2  = (const float*)d_in[8];
    const float* ar2  = (const float*)d_in[9];
    const float* b2   = (const float*)d_in[10];
    const float* W3   = (const float*)d_in[11];
    const float* al3  = (const float*)d_in[12];
    const float* ar3  = (const float*)d_in[13];
    const float* b3   = (const float*)d_in[14];

    const int E = in_sizes[1];
    const int rows = NN * NH;

    // ---- workspace bump allocator (256B aligned) ----
    char* ws = (char*)d_ws;
    size_t o = 0;
    auto alloc = [&](size_t bytes) -> char* {
        o = (o + 255) & ~(size_t)255;
        char* p = ws + o;
        o += bytes;
        return p;
    };
    int*   cnt     = (int*)alloc((size_t)NN * 4);
    int*   off     = (int*)alloc((size_t)(NN + 1) * 4);
    int*   cur     = (int*)alloc((size_t)NN * 4);
    int*   csr_src = (int*)alloc((size_t)E * 4);
    ushortT* featb = (ushortT*)alloc((size_t)NN * FFP * 2);
    ushortT* W1T   = (ushortT*)alloc((size_t)256 * FFP * 2);
    ushortT* W2T   = (ushortT*)alloc((size_t)128 * 256 * 2);
    float* h1      = (float*)alloc((size_t)NN * 256 * 4);
    float* el1     = (float*)alloc((size_t)rows * 4);
    float* er1     = (float*)alloc((size_t)rows * 4);
    float* agg1    = (float*)alloc((size_t)NN * 256 * 4);
    ushortT* out1b = (ushortT*)alloc((size_t)NN * 256 * 2);
    float* h2      = (float*)alloc((size_t)NN * 128 * 4);
    float* el2     = (float*)alloc((size_t)rows * 4);
    float* er2     = (float*)alloc((size_t)rows * 4);
    float* agg2    = (float*)alloc((size_t)NN * 128 * 4);
    float* z       = (float*)alloc((size_t)NN * 64 * 4);
    ushortT* zb    = (ushortT*)alloc((size_t)NN * 64 * 2);
    float* wl3     = (float*)alloc(128 * 4);
    float* wr3     = (float*)alloc(128 * 4);
    float* el3     = (float*)alloc((size_t)rows * 4);
    float* er3     = (float*)alloc((size_t)rows * 4);
    float* zagg    = (float*)alloc((size_t)NN * 128 * 4);

    float* a_hat = (float*)d_out;
    float* x_hat = (float*)d_out + (size_t)NN * NN;

    // ---- CSR build ----
    zero_int_kernel<<<(NN + 255) / 256, 256, 0, stream>>>(cnt, NN);
    count_dst_kernel<<<(E + 255) / 256, 256, 0, stream>>>(dst, cnt, E);
    scan_offsets_kernel<<<1, 1024, 0, stream>>>(cnt, off, cur, NN);
    scatter_kernel<<<(E + 255) / 256, 256, 0, stream>>>(src, dst, cur, csr_src, E);

    // ---- bf16 weight/feature prep ----
    cast_pad_kernel<<<NN, 256, 0, stream>>>(feat, featb, FF, FFP);
    transpose_cast_kernel<<<256, 256, 0, stream>>>(W1, W1T, FF, 256, FFP);
    transpose_cast_kernel<<<128, 256, 0, stream>>>(W2, W2T, 256, 128, 256);

    // ---- layer 1 ----
    {
        dim3 g(256 / 128, NN / 128);
        bt_mfma_kernel<<<g, 256, 0, stream>>>(featb, W1T, h1, FFP, 256);
    }
    attn_scores_kernel<128><<<rows / 4, 256, 0, stream>>>(h1, al1, ar1, el1, er1, rows);
    gat_aggregate_kernel<128, false><<<rows / 4, 256, 0, stream>>>(off, csr_src, el1, er1, h1, agg1, rows);
    ep1_kernel<<<(NN * 256 + 255) / 256, 256, 0, stream>>>(agg1, b1, out1b, NN * 256);

    // ---- layer 2 ----
    {
        dim3 g(1, NN / 128);
        bt_mfma_kernel<<<g, 256, 0, stream>>>(out1b, W2T, h2, 256, 128);
    }
    attn_scores_kernel<64><<<rows / 4, 256, 0, stream>>>(h2, al2, ar2, el2, er2, rows);
    gat_aggregate_kernel<64, false><<<rows / 4, 256, 0, stream>>>(off, csr_src, el2, er2, h2, agg2, rows);
    ep2_kernel<<<(NN * 64 + 255) / 256, 256, 0, stream>>>(agg2, b2, z, zb, NN * 64);

    // ---- layer 3 (attr decoder), aggregation pushed before GEMM ----
    w3_vec_kernel<<<32, 256, 0, stream>>>(W3, al3, ar3, wl3, wr3);
    attn_scores_shared_kernel<<<rows / 4, 256, 0, stream>>>(z, wl3, wr3, el3, er3, rows);
    gat_aggregate_kernel<64, true><<<rows / 4, 256, 0, stream>>>(off, csr_src, el3, er3, z, zagg, rows);
    xhat_kernel<<<NN / 8, 256, 0, stream>>>(zagg, W3, b3, x_hat);

    // ---- structure decoder: a_hat = z @ z^T via bf16 MFMA ----
    {
        dim3 g(NN / 128, NN / 128);
        bt_mfma_kernel<<<g, 256, 0, stream>>>(zb, zb, a_hat, 64, NN);
    }
}